// Round 1
// baseline (883.522 us; speedup 1.0000x reference)
//
#include <hip/hip_runtime.h>
#include <cmath>

#define GG 20000
#define NN 2048
#define PP 200
#define SS 128
#define EE 128
#define TN 32
#define TPP 25
#define NSPLIT 8
#define SC 64

// static device scratch (avoids relying on ws_size)
__device__ float g_ctx[(size_t)NN * NSPLIT * EE];   // 8.4 MB
__device__ float g_m[NN * NSPLIT];
__device__ float g_l[NN * NSPLIT];
__device__ float g_pcn[NN * 2];

// ---------------------------------------------------------------------------
// Phase A: gathered projection GEMM + bias + relu + online-softmax partials
// grid (64, 8), block 256.  Each block: 32 n-rows x 25 pathways.
// ---------------------------------------------------------------------------
__global__ __launch_bounds__(256, 2) void proj_attn_kernel(
    const float* __restrict__ x, const int* __restrict__ tidx,
    const int* __restrict__ pidx, const float* __restrict__ Wp,
    const float* __restrict__ bp, const float* __restrict__ tt)
{
  __shared__ float xg[SS][TN];     // 16 KB, [s][i]
  __shared__ float wp[SC][EE];     // 32 KB, [s][e] xor-swizzled 16B slots
  __shared__ float qa[TN][EE];     // 16 KB
  __shared__ int   sidx[SS];
  __shared__ float sbp[EE];

  const int t = threadIdx.x;
  const int n0 = blockIdx.x * TN;
  const int split = blockIdx.y;
  const int p0 = split * TPP;
  const int ei = t & 31, ii = t >> 5;
  const int e0 = ei * 4, i0 = ii * 4;

  // stage Q = tissue_table[tissue_idx[n]] once per block
  #pragma unroll
  for (int j = 0; j < (TN * EE) / 256; ++j) {
    int flat = t + j * 256;
    int i = flat >> 7, e = flat & 127;
    qa[i][e] = tt[tidx[n0 + i] * EE + e];
  }

  float m[4], l[4], ctx[4][4];
  #pragma unroll
  for (int r = 0; r < 4; ++r) {
    m[r] = -1e30f; l[r] = 0.f;
    #pragma unroll
    for (int c = 0; c < 4; ++c) ctx[r][c] = 0.f;
  }

  for (int pp = 0; pp < TPP; ++pp) {
    const int p = p0 + pp;
    __syncthreads();                       // protect sidx/sbp/xg from prev iter readers
    if (t < SS) sidx[t] = pidx[p * SS + t];
    else        sbp[t - SS] = bp[p * EE + (t - SS)];
    __syncthreads();

    // gather xg[s][i] = x[n0+i][ sidx[s] ]
    {
      const int gi = t & 31, sb = t >> 5;
      const float* xrow = x + (size_t)(n0 + gi) * GG;
      #pragma unroll
      for (int j = 0; j < 16; ++j) {
        int s = sb + j * 8;
        xg[s][gi] = xrow[sidx[s]];
      }
    }

    float acc[4][4];
    #pragma unroll
    for (int r = 0; r < 4; ++r)
      #pragma unroll
      for (int c = 0; c < 4; ++c) acc[r][c] = 0.f;

    for (int ch = 0; ch < SS / SC; ++ch) {
      __syncthreads();  // prev chunk compute done (and gather visible on ch==0)
      // stage W_proj[p][:, ch*SC .. +SC) transposed into wp[sl][e], swizzled
      {
        const int sl = t & 63, eq = t >> 6;
        const float* wpp = Wp + (size_t)p * EE * SS + ch * SC;
        #pragma unroll
        for (int j = 0; j < 8; ++j) {
          int q = eq * 8 + j;          // e-quad 0..31
          int eb = q * 4;
          float4 v;
          v.x = wpp[(eb + 0) * SS + sl];
          v.y = wpp[(eb + 1) * SS + sl];
          v.z = wpp[(eb + 2) * SS + sl];
          v.w = wpp[(eb + 3) * SS + sl];
          int slot = q ^ (sl & 31);
          *(float4*)&wp[sl][slot << 2] = v;
        }
      }
      __syncthreads();

      #pragma unroll 8
      for (int sl = 0; sl < SC; ++sl) {
        const int s = ch * SC + sl;
        const float4 xv = *(const float4*)&xg[s][i0];
        const float4 wv = *(const float4*)&wp[sl][((ei ^ (sl & 31)) << 2)];
        const float xr[4] = {xv.x, xv.y, xv.z, xv.w};
        const float wc[4] = {wv.x, wv.y, wv.z, wv.w};
        #pragma unroll
        for (int r = 0; r < 4; ++r)
          #pragma unroll
          for (int c = 0; c < 4; ++c) acc[r][c] += xr[r] * wc[c];
      }
    }

    // bias + relu + score, then online-softmax update
    const float4 bpv = *(const float4*)&sbp[e0];
    float scr[4];
    #pragma unroll
    for (int r = 0; r < 4; ++r) {
      const float4 qv = *(const float4*)&qa[i0 + r][e0];
      float h0 = fmaxf(acc[r][0] + bpv.x, 0.f);
      float h1 = fmaxf(acc[r][1] + bpv.y, 0.f);
      float h2 = fmaxf(acc[r][2] + bpv.z, 0.f);
      float h3 = fmaxf(acc[r][3] + bpv.w, 0.f);
      acc[r][0] = h0; acc[r][1] = h1; acc[r][2] = h2; acc[r][3] = h3;
      scr[r] = h0 * qv.x + h1 * qv.y + h2 * qv.z + h3 * qv.w;
    }
    #pragma unroll
    for (int off = 16; off >= 1; off >>= 1)
      #pragma unroll
      for (int r = 0; r < 4; ++r) scr[r] += __shfl_xor(scr[r], off);

    const float SCALE = 0.08838834764831845f;  // 1/sqrt(128)
    #pragma unroll
    for (int r = 0; r < 4; ++r) {
      float s_r = scr[r] * SCALE;
      float mn = fmaxf(m[r], s_r);
      float f = expf(m[r] - mn);
      float w = expf(s_r - mn);
      l[r] = l[r] * f + w;
      m[r] = mn;
      #pragma unroll
      for (int c = 0; c < 4; ++c) ctx[r][c] = ctx[r][c] * f + w * acc[r][c];
    }
  }

  // write partials
  #pragma unroll
  for (int r = 0; r < 4; ++r) {
    int n = n0 + i0 + r;
    float4 cv = make_float4(ctx[r][0], ctx[r][1], ctx[r][2], ctx[r][3]);
    *(float4*)&g_ctx[((size_t)n * NSPLIT + split) * EE + e0] = cv;
    if (ei == 0) {
      g_m[n * NSPLIT + split] = m[r];
      g_l[n * NSPLIT + split] = l[r];
    }
  }
}

// ---------------------------------------------------------------------------
// Phase B: merge softmax splits, MLP, pcn + angle.  grid 2048, block 64.
// ---------------------------------------------------------------------------
__global__ __launch_bounds__(64) void combine_kernel(
    const float* __restrict__ W1, const float* __restrict__ b1,
    const float* __restrict__ W2, const float* __restrict__ b2,
    float* __restrict__ out)
{
  const int n = blockIdx.x;
  const int t = threadIdx.x;
  __shared__ float ctxs[EE];

  float ms[NSPLIT], ls[NSPLIT];
  float M = -1e30f;
  #pragma unroll
  for (int s = 0; s < NSPLIT; ++s) {
    ms[s] = g_m[n * NSPLIT + s];
    ls[s] = g_l[n * NSPLIT + s];
    M = fmaxf(M, ms[s]);
  }
  float w[NSPLIT];
  float L = 0.f;
  #pragma unroll
  for (int s = 0; s < NSPLIT; ++s) { w[s] = expf(ms[s] - M); L += ls[s] * w[s]; }
  const float invL = 1.f / L;

  float c0 = 0.f, c1 = 0.f;
  #pragma unroll
  for (int s = 0; s < NSPLIT; ++s) {
    const float* base = &g_ctx[((size_t)n * NSPLIT + s) * EE];
    c0 += w[s] * base[t];
    c1 += w[s] * base[t + 64];
  }
  ctxs[t] = c0 * invL;
  ctxs[t + 64] = c1 * invL;
  __syncthreads();

  const int k = t & 31;
  float h = 0.f;
  for (int e = 0; e < EE; ++e) h += ctxs[e] * W1[e * 32 + k];
  h = fmaxf(h + b1[k], 0.f);

  float p0 = h * W2[k * 2 + 0];
  float p1 = h * W2[k * 2 + 1];
  #pragma unroll
  for (int off = 16; off >= 1; off >>= 1) {
    p0 += __shfl_xor(p0, off);
    p1 += __shfl_xor(p1, off);
  }
  p0 += b2[0];
  p1 += b2[1];

  const float nrm = sqrtf(p0 * p0 + p1 * p1);
  const float inv = 1.f / fmaxf(nrm, 1e-12f);
  const float q0 = p0 * inv, q1 = p1 * inv;
  const float PI2 = 6.2831853071795864769f;
  float ang = atan2f(q1, q0) + PI2;
  if (ang >= PI2) ang -= PI2;

  if (t == 0) {
    out[n * 2 + 0] = q0;
    out[n * 2 + 1] = q1;
    out[2 * NN + n] = ang;
    g_pcn[n * 2 + 0] = q0;
    g_pcn[n * 2 + 1] = q1;
  }
}

// ---------------------------------------------------------------------------
// Phase C: rec = l2norm(pcn @ Wdec + bdec).  grid 2048, block 256.
// ---------------------------------------------------------------------------
__global__ __launch_bounds__(256) void rec_kernel(
    const float* __restrict__ Wdec, const float* __restrict__ bdec,
    float* __restrict__ out)
{
  const int n = blockIdx.x;
  const int t = threadIdx.x;
  __shared__ float v[GG];          // 80 KB
  __shared__ float red[4];

  const float q0 = g_pcn[n * 2 + 0];
  const float q1 = g_pcn[n * 2 + 1];

  float ss = 0.f;
  for (int g = t; g < GG; g += 256) {
    float val = q0 * Wdec[g] + q1 * Wdec[GG + g] + bdec[g];
    v[g] = val;
    ss += val * val;
  }
  #pragma unroll
  for (int off = 32; off >= 1; off >>= 1) ss += __shfl_xor(ss, off);
  if ((t & 63) == 0) red[t >> 6] = ss;
  __syncthreads();
  const float total = red[0] + red[1] + red[2] + red[3];
  const float inv = 1.f / fmaxf(sqrtf(total), 1e-12f);

  float* outrec = out + 3 * NN + (size_t)n * GG;
  for (int g = t; g < GG; g += 256) outrec[g] = v[g] * inv;
}

// ---------------------------------------------------------------------------
extern "C" void kernel_launch(void* const* d_in, const int* in_sizes, int n_in,
                              void* d_out, int out_size, void* d_ws, size_t ws_size,
                              hipStream_t stream) {
  (void)in_sizes; (void)n_in; (void)out_size; (void)d_ws; (void)ws_size;
  const float* x    = (const float*)d_in[0];
  const int*   tidx = (const int*)  d_in[1];
  const int*   pidx = (const int*)  d_in[2];
  const float* Wp   = (const float*)d_in[3];
  const float* bp   = (const float*)d_in[4];
  const float* tt   = (const float*)d_in[5];
  const float* W1   = (const float*)d_in[6];
  const float* b1   = (const float*)d_in[7];
  const float* W2   = (const float*)d_in[8];
  const float* b2   = (const float*)d_in[9];
  const float* Wdec = (const float*)d_in[10];
  const float* bdec = (const float*)d_in[11];
  float* out = (float*)d_out;

  dim3 gridA(NN / TN, NSPLIT, 1);          // 64 x 8
  proj_attn_kernel<<<gridA, 256, 0, stream>>>(x, tidx, pidx, Wp, bp, tt);
  combine_kernel<<<NN, 64, 0, stream>>>(W1, b1, W2, b2, out);
  rec_kernel<<<NN, 256, 0, stream>>>(Wdec, bdec, out);
}

// Round 2
// 864.198 us; speedup vs baseline: 1.0224x; 1.0224x over previous
//
#include <hip/hip_runtime.h>
#include <cmath>

#define GG 20000
#define NN 2048
#define PP 200
#define SS 128
#define EE 128
#define TN 32
#define TPP 25
#define NSPLIT 8
#define SC2 32
#define GTILE 64

// static device scratch
__device__ float g_xT[(size_t)GG * NN];             // 164 MB transposed x
__device__ float g_ctx[(size_t)NN * NSPLIT * EE];   // 8.4 MB
__device__ float g_m[NN * NSPLIT];
__device__ float g_l[NN * NSPLIT];
__device__ float g_pcn[NN * 2];

// ---------------------------------------------------------------------------
// Phase 0: transpose x (2048 x 20000) -> xT (20000 x 2048)
// ---------------------------------------------------------------------------
__global__ __launch_bounds__(256) void transpose_kernel(
    const float* __restrict__ x, float* __restrict__ xT)
{
  __shared__ float tile[GTILE][GTILE + 1];
  const int g0 = blockIdx.x * GTILE;
  const int n0 = blockIdx.y * GTILE;
  const int t = threadIdx.x;
  const int tx = t & 63;
  const int ty = t >> 6;   // 0..3

  #pragma unroll
  for (int k = 0; k < 16; ++k) {
    int g = g0 + tx;
    int nl = ty + 4 * k;
    if (g < GG) tile[tx][nl] = x[(size_t)(n0 + nl) * GG + g];
  }
  __syncthreads();
  #pragma unroll
  for (int k = 0; k < 16; ++k) {
    int gl = ty + 4 * k;
    int g = g0 + gl;
    if (g < GG) xT[(size_t)g * NN + n0 + tx] = tile[gl][tx];
  }
}

// ---------------------------------------------------------------------------
// Phase A: gathered projection GEMM + bias + relu + online-softmax partials
// grid (64, 8), block 256.  Each block: 32 n-rows x 25 pathways.
// ---------------------------------------------------------------------------
__global__ __launch_bounds__(256, 4) void proj_attn_kernel(
    const float* __restrict__ xT, const int* __restrict__ tidx,
    const int* __restrict__ pidx, const float* __restrict__ Wp,
    const float* __restrict__ bp, const float* __restrict__ tt)
{
  __shared__ float xg[SS][TN];     // 16 KB, [s][i]
  __shared__ float wp[SC2][EE];    // 16 KB, [s][e] xor-swizzled quads
  __shared__ int   sidx[SS];
  __shared__ float sbp[EE];

  const int t = threadIdx.x;
  const int n0 = blockIdx.x * TN;
  const int split = blockIdx.y;
  const int p0 = split * TPP;
  const int ei = t & 31, ii = t >> 5;
  const int e0 = ei * 4, i0 = ii * 4;

  // Q in registers: qr[r][c] = tt[tidx[n0+i0+r]][e0+c]
  float qr[4][4];
  #pragma unroll
  for (int r = 0; r < 4; ++r) {
    int ti = tidx[n0 + i0 + r];
    float4 qv = *(const float4*)&tt[(size_t)ti * EE + e0];
    qr[r][0] = qv.x; qr[r][1] = qv.y; qr[r][2] = qv.z; qr[r][3] = qv.w;
  }

  float m[4], l[4], ctx[4][4];
  #pragma unroll
  for (int r = 0; r < 4; ++r) {
    m[r] = -1e30f; l[r] = 0.f;
    #pragma unroll
    for (int c = 0; c < 4; ++c) ctx[r][c] = 0.f;
  }

  for (int pp = 0; pp < TPP; ++pp) {
    const int p = p0 + pp;
    __syncthreads();                       // prev pathway done reading xg/sidx
    if (t < SS) sidx[t] = pidx[p * SS + t];
    else        sbp[t - SS] = bp[p * EE + (t - SS)];
    __syncthreads();

    // gather xg[s][i] = xT[sidx[s]][n0+i]  (coalesced 128B per s-row)
    {
      const int gi = t & 31, sb = t >> 5;
      #pragma unroll
      for (int j = 0; j < 16; ++j) {
        int s = sb * 16 + j;
        xg[s][gi] = xT[(size_t)sidx[s] * NN + n0 + gi];
      }
    }

    float acc[4][4];
    #pragma unroll
    for (int r = 0; r < 4; ++r)
      #pragma unroll
      for (int c = 0; c < 4; ++c) acc[r][c] = 0.f;

    for (int ch = 0; ch < SS / SC2; ++ch) {
      __syncthreads();  // prev chunk compute done (and gather visible on ch==0)
      // stage W_proj[p][:, ch*SC2 ..) transposed into wp[sl][e], quad-swizzled
      {
        const int sl = t & 31, er = t >> 5;   // er 0..7
        const float* wpp = Wp + (size_t)p * EE * SS + ch * SC2 + sl;
        const int swz = (sl & 7) << 2;
        #pragma unroll
        for (int j = 0; j < 16; ++j) {
          int e = er * 16 + j;
          wp[sl][e ^ swz] = wpp[(size_t)e * SS];
        }
      }
      __syncthreads();

      #pragma unroll 8
      for (int sl = 0; sl < SC2; ++sl) {
        const int s = ch * SC2 + sl;
        const float4 xv = *(const float4*)&xg[s][i0];
        const float4 wv = *(const float4*)&wp[sl][e0 ^ ((sl & 7) << 2)];
        const float xr[4] = {xv.x, xv.y, xv.z, xv.w};
        const float wc[4] = {wv.x, wv.y, wv.z, wv.w};
        #pragma unroll
        for (int r = 0; r < 4; ++r)
          #pragma unroll
          for (int c = 0; c < 4; ++c) acc[r][c] += xr[r] * wc[c];
      }
    }

    // bias + relu + score, then online-softmax update
    const float4 bpv = *(const float4*)&sbp[e0];
    float scr[4];
    #pragma unroll
    for (int r = 0; r < 4; ++r) {
      float h0 = fmaxf(acc[r][0] + bpv.x, 0.f);
      float h1 = fmaxf(acc[r][1] + bpv.y, 0.f);
      float h2 = fmaxf(acc[r][2] + bpv.z, 0.f);
      float h3 = fmaxf(acc[r][3] + bpv.w, 0.f);
      acc[r][0] = h0; acc[r][1] = h1; acc[r][2] = h2; acc[r][3] = h3;
      scr[r] = h0 * qr[r][0] + h1 * qr[r][1] + h2 * qr[r][2] + h3 * qr[r][3];
    }
    #pragma unroll
    for (int off = 16; off >= 1; off >>= 1)
      #pragma unroll
      for (int r = 0; r < 4; ++r) scr[r] += __shfl_xor(scr[r], off);

    const float SCALE = 0.08838834764831845f;  // 1/sqrt(128)
    #pragma unroll
    for (int r = 0; r < 4; ++r) {
      float s_r = scr[r] * SCALE;
      float mn = fmaxf(m[r], s_r);
      float f = expf(m[r] - mn);
      float w = expf(s_r - mn);
      l[r] = l[r] * f + w;
      m[r] = mn;
      #pragma unroll
      for (int c = 0; c < 4; ++c) ctx[r][c] = ctx[r][c] * f + w * acc[r][c];
    }
  }

  // write partials
  #pragma unroll
  for (int r = 0; r < 4; ++r) {
    int n = n0 + i0 + r;
    float4 cv = make_float4(ctx[r][0], ctx[r][1], ctx[r][2], ctx[r][3]);
    *(float4*)&g_ctx[((size_t)n * NSPLIT + split) * EE + e0] = cv;
    if (ei == 0) {
      g_m[n * NSPLIT + split] = m[r];
      g_l[n * NSPLIT + split] = l[r];
    }
  }
}

// ---------------------------------------------------------------------------
// Phase B: merge softmax splits, MLP, pcn + angle.  grid 2048, block 64.
// ---------------------------------------------------------------------------
__global__ __launch_bounds__(64) void combine_kernel(
    const float* __restrict__ W1, const float* __restrict__ b1,
    const float* __restrict__ W2, const float* __restrict__ b2,
    float* __restrict__ out)
{
  const int n = blockIdx.x;
  const int t = threadIdx.x;
  __shared__ float ctxs[EE];

  float ms[NSPLIT], ls[NSPLIT];
  float M = -1e30f;
  #pragma unroll
  for (int s = 0; s < NSPLIT; ++s) {
    ms[s] = g_m[n * NSPLIT + s];
    ls[s] = g_l[n * NSPLIT + s];
    M = fmaxf(M, ms[s]);
  }
  float w[NSPLIT];
  float L = 0.f;
  #pragma unroll
  for (int s = 0; s < NSPLIT; ++s) { w[s] = expf(ms[s] - M); L += ls[s] * w[s]; }
  const float invL = 1.f / L;

  float c0 = 0.f, c1 = 0.f;
  #pragma unroll
  for (int s = 0; s < NSPLIT; ++s) {
    const float* base = &g_ctx[((size_t)n * NSPLIT + s) * EE];
    c0 += w[s] * base[t];
    c1 += w[s] * base[t + 64];
  }
  ctxs[t] = c0 * invL;
  ctxs[t + 64] = c1 * invL;
  __syncthreads();

  const int k = t & 31;
  float h = 0.f;
  for (int e = 0; e < EE; ++e) h += ctxs[e] * W1[e * 32 + k];
  h = fmaxf(h + b1[k], 0.f);

  float p0 = h * W2[k * 2 + 0];
  float p1 = h * W2[k * 2 + 1];
  #pragma unroll
  for (int off = 16; off >= 1; off >>= 1) {
    p0 += __shfl_xor(p0, off);
    p1 += __shfl_xor(p1, off);
  }
  p0 += b2[0];
  p1 += b2[1];

  const float nrm = sqrtf(p0 * p0 + p1 * p1);
  const float inv = 1.f / fmaxf(nrm, 1e-12f);
  const float q0 = p0 * inv, q1 = p1 * inv;
  const float PI2 = 6.2831853071795864769f;
  float ang = atan2f(q1, q0) + PI2;
  if (ang >= PI2) ang -= PI2;

  if (t == 0) {
    out[n * 2 + 0] = q0;
    out[n * 2 + 1] = q1;
    out[2 * NN + n] = ang;
    g_pcn[n * 2 + 0] = q0;
    g_pcn[n * 2 + 1] = q1;
  }
}

// ---------------------------------------------------------------------------
// Phase C: rec = l2norm(pcn @ Wdec + bdec).  grid 2048, block 256, no big LDS
// (Wdec/bdec are L2-resident; recompute instead of staging 80 KB).
// ---------------------------------------------------------------------------
__global__ __launch_bounds__(256) void rec_kernel(
    const float* __restrict__ Wdec, const float* __restrict__ bdec,
    float* __restrict__ out)
{
  const int n = blockIdx.x;
  const int t = threadIdx.x;
  __shared__ float red[4];

  const float q0 = g_pcn[n * 2 + 0];
  const float q1 = g_pcn[n * 2 + 1];

  float ss = 0.f;
  for (int g = t; g < GG; g += 256) {
    float val = q0 * Wdec[g] + q1 * Wdec[GG + g] + bdec[g];
    ss += val * val;
  }
  #pragma unroll
  for (int off = 32; off >= 1; off >>= 1) ss += __shfl_xor(ss, off);
  if ((t & 63) == 0) red[t >> 6] = ss;
  __syncthreads();
  const float total = red[0] + red[1] + red[2] + red[3];
  const float inv = 1.f / fmaxf(sqrtf(total), 1e-12f);

  float* outrec = out + 3 * NN + (size_t)n * GG;
  for (int g = t; g < GG; g += 256) {
    float val = q0 * Wdec[g] + q1 * Wdec[GG + g] + bdec[g];
    outrec[g] = val * inv;
  }
}

// ---------------------------------------------------------------------------
extern "C" void kernel_launch(void* const* d_in, const int* in_sizes, int n_in,
                              void* d_out, int out_size, void* d_ws, size_t ws_size,
                              hipStream_t stream) {
  (void)in_sizes; (void)n_in; (void)out_size; (void)d_ws; (void)ws_size;
  const float* x    = (const float*)d_in[0];
  const int*   tidx = (const int*)  d_in[1];
  const int*   pidx = (const int*)  d_in[2];
  const float* Wp   = (const float*)d_in[3];
  const float* bp   = (const float*)d_in[4];
  const float* tt   = (const float*)d_in[5];
  const float* W1   = (const float*)d_in[6];
  const float* b1   = (const float*)d_in[7];
  const float* W2   = (const float*)d_in[8];
  const float* b2   = (const float*)d_in[9];
  const float* Wdec = (const float*)d_in[10];
  const float* bdec = (const float*)d_in[11];
  float* out = (float*)d_out;

  float* xT;
  hipGetSymbolAddress((void**)&xT, HIP_SYMBOL(g_xT));

  dim3 gridT((GG + GTILE - 1) / GTILE, NN / GTILE, 1);   // 313 x 32
  transpose_kernel<<<gridT, 256, 0, stream>>>(x, xT);

  dim3 gridA(NN / TN, NSPLIT, 1);          // 64 x 8
  proj_attn_kernel<<<gridA, 256, 0, stream>>>(xT, tidx, pidx, Wp, bp, tt);
  combine_kernel<<<NN, 64, 0, stream>>>(W1, b1, W2, b2, out);
  rec_kernel<<<NN, 256, 0, stream>>>(Wdec, bdec, out);
}

// Round 3
// 490.560 us; speedup vs baseline: 1.8010x; 1.7617x over previous
//
#include <hip/hip_runtime.h>
#include <cmath>

#define GG 20000
#define NN 2048
#define PP 200
#define SS 128
#define EE 128
#define TT_ 50
#define TN 128
#define TPP 4
#define NSPLIT 50
#define SC 32

// static device scratch
__device__ float g_xT[(size_t)GG * NN];             // 164 MB transposed x
__device__ float g_ctx[(size_t)NN * NSPLIT * EE];   // 52 MB
__device__ float g_m[NN * NSPLIT];
__device__ float g_l[NN * NSPLIT];

// ---------------------------------------------------------------------------
// Phase 0: transpose x (2048 x 20000) -> xT (20000 x 2048), float4 both sides
// ---------------------------------------------------------------------------
__global__ __launch_bounds__(256) void transpose_kernel(
    const float* __restrict__ x, float* __restrict__ xT)
{
  __shared__ float tile[64][65];
  const int g0 = blockIdx.x * 64;
  const int n0 = blockIdx.y * 64;
  const int t = threadIdx.x;

  {
    const int gq = t & 15, nl4 = t >> 4;
    #pragma unroll
    for (int k = 0; k < 4; ++k) {
      int nl = nl4 + 16 * k;
      int g = g0 + gq * 4;
      if (g < GG) {
        float4 v = *(const float4*)&x[(size_t)(n0 + nl) * GG + g];
        tile[gq * 4 + 0][nl] = v.x;
        tile[gq * 4 + 1][nl] = v.y;
        tile[gq * 4 + 2][nl] = v.z;
        tile[gq * 4 + 3][nl] = v.w;
      }
    }
  }
  __syncthreads();
  {
    const int nq = t & 15, gl4 = t >> 4;
    #pragma unroll
    for (int k = 0; k < 4; ++k) {
      int gl = gl4 + 16 * k;
      int g = g0 + gl;
      if (g < GG) {
        float4 v = make_float4(tile[gl][nq * 4 + 0], tile[gl][nq * 4 + 1],
                               tile[gl][nq * 4 + 2], tile[gl][nq * 4 + 3]);
        *(float4*)&xT[(size_t)g * NN + n0 + nq * 4] = v;
      }
    }
  }
}

// ---------------------------------------------------------------------------
// Phase A: gathered projection GEMM + bias + relu + online-softmax partials
// grid (16, 50), block 256.  Block: 128 n-rows x 4 pathways, 8x8 reg tile.
// Lane layout: eg = t&15 (e = eg*8+c), ig = t>>4 (i = ig*8+r).
// ---------------------------------------------------------------------------
__global__ __launch_bounds__(256, 2) void proj_attn_kernel(
    const float* __restrict__ xT, const int* __restrict__ tidx,
    const int* __restrict__ pidx, const float* __restrict__ Wp,
    const float* __restrict__ bp, const float* __restrict__ tt)
{
  __shared__ float tt_lds[TT_][132];   // 26.4 KB padded tissue table
  __shared__ float xg[SC][TN];         // 16 KB  [s][n]
  __shared__ float wp[SC][EE];         // 16 KB  [s][e] xor-quad swizzled
  __shared__ int   sidx[SS];
  __shared__ float sbp[EE];

  const int t = threadIdx.x;
  const int n0 = blockIdx.x * TN;
  const int split = blockIdx.y;
  const int eg = t & 15;
  const int ig = t >> 4;

  for (int f = t; f < TT_ * EE; f += 256) tt_lds[f >> 7][f & 127] = tt[f];

  int tid8[8];
  #pragma unroll
  for (int r = 0; r < 8; ++r) tid8[r] = tidx[n0 + ig * 8 + r];

  float m[8], l[8], ctx[8][8];
  #pragma unroll
  for (int r = 0; r < 8; ++r) {
    m[r] = -1e30f; l[r] = 0.f;
    #pragma unroll
    for (int c = 0; c < 8; ++c) ctx[r][c] = 0.f;
  }

  for (int pp = 0; pp < TPP; ++pp) {
    const int p = split * TPP + pp;
    __syncthreads();                        // A: prev pathway fully consumed
    if (t < 128) sidx[t] = pidx[p * SS + t];
    else         sbp[t - 128] = bp[p * EE + (t - 128)];
    __syncthreads();                        // B

    float acc[8][8];
    #pragma unroll
    for (int r = 0; r < 8; ++r)
      #pragma unroll
      for (int c = 0; c < 8; ++c) acc[r][c] = 0.f;

    for (int ch = 0; ch < SS / SC; ++ch) {
      if (ch) __syncthreads();              // C: prev chunk compute done
      // stage xg[sl][n]: float4 gather rows
      {
        const int c4 = t & 31, r8 = t >> 5;
        #pragma unroll
        for (int j = 0; j < 4; ++j) {
          int sl = r8 + j * 8;
          int g = sidx[ch * SC + sl];
          float4 v = *(const float4*)&xT[(size_t)g * NN + n0 + c4 * 4];
          *(float4*)&xg[sl][c4 * 4] = v;
        }
      }
      // stage wp[sl][e] swizzled: col quad = (e>>2) ^ sl
      {
        const int sl = t & 31, eb = (t >> 5) * 16;
        const float* wrow = Wp + (size_t)p * EE * SS + ch * SC + sl;
        #pragma unroll
        for (int j = 0; j < 16; ++j) {
          int e = eb + j;
          float v = wrow[(size_t)e * SS];
          int col = ((((e >> 2) ^ sl) & 31) << 2) | (e & 3);
          wp[sl][col] = v;
        }
      }
      __syncthreads();                      // D
      #pragma unroll 2
      for (int sl = 0; sl < SC; ++sl) {
        float4 xv0 = *(const float4*)&xg[sl][ig * 8];
        float4 xv1 = *(const float4*)&xg[sl][ig * 8 + 4];
        float4 wv0 = *(const float4*)&wp[sl][((((eg * 2) ^ sl) & 31) << 2)];
        float4 wv1 = *(const float4*)&wp[sl][((((eg * 2 + 1) ^ sl) & 31) << 2)];
        float xr[8] = {xv0.x, xv0.y, xv0.z, xv0.w, xv1.x, xv1.y, xv1.z, xv1.w};
        float wc[8] = {wv0.x, wv0.y, wv0.z, wv0.w, wv1.x, wv1.y, wv1.z, wv1.w};
        #pragma unroll
        for (int r = 0; r < 8; ++r)
          #pragma unroll
          for (int c = 0; c < 8; ++c) acc[r][c] += xr[r] * wc[c];
      }
    }

    // bias + relu + score + online-softmax
    float4 bb0 = *(const float4*)&sbp[eg * 8];
    float4 bb1 = *(const float4*)&sbp[eg * 8 + 4];
    const float bbv[8] = {bb0.x, bb0.y, bb0.z, bb0.w, bb1.x, bb1.y, bb1.z, bb1.w};
    float scr[8];
    #pragma unroll
    for (int r = 0; r < 8; ++r) {
      float4 q0 = *(const float4*)&tt_lds[tid8[r]][eg * 8];
      float4 q1 = *(const float4*)&tt_lds[tid8[r]][eg * 8 + 4];
      const float qv[8] = {q0.x, q0.y, q0.z, q0.w, q1.x, q1.y, q1.z, q1.w};
      float s_r = 0.f;
      #pragma unroll
      for (int c = 0; c < 8; ++c) {
        float h = fmaxf(acc[r][c] + bbv[c], 0.f);
        acc[r][c] = h;
        s_r += h * qv[c];
      }
      scr[r] = s_r;
    }
    #pragma unroll
    for (int off = 8; off >= 1; off >>= 1)
      #pragma unroll
      for (int r = 0; r < 8; ++r) scr[r] += __shfl_xor(scr[r], off);

    const float SCALE = 0.08838834764831845f;  // 1/sqrt(128)
    #pragma unroll
    for (int r = 0; r < 8; ++r) {
      float s_r = scr[r] * SCALE;
      float mn = fmaxf(m[r], s_r);
      float f = expf(m[r] - mn);
      float w = expf(s_r - mn);
      l[r] = l[r] * f + w;
      m[r] = mn;
      #pragma unroll
      for (int c = 0; c < 8; ++c) ctx[r][c] = ctx[r][c] * f + w * acc[r][c];
    }
  }

  // epilogue: write partials
  #pragma unroll
  for (int r = 0; r < 8; ++r) {
    int n = n0 + ig * 8 + r;
    size_t base = ((size_t)n * NSPLIT + split) * EE + eg * 8;
    *(float4*)&g_ctx[base]     = make_float4(ctx[r][0], ctx[r][1], ctx[r][2], ctx[r][3]);
    *(float4*)&g_ctx[base + 4] = make_float4(ctx[r][4], ctx[r][5], ctx[r][6], ctx[r][7]);
    if (eg == 0) {
      g_m[n * NSPLIT + split] = m[r];
      g_l[n * NSPLIT + split] = l[r];
    }
  }
}

// ---------------------------------------------------------------------------
// Phase B: merge splits + MLP + pcn/ang + rec, one block per n.  block 256.
// ---------------------------------------------------------------------------
__global__ __launch_bounds__(256) void rec_combine_kernel(
    const float* __restrict__ W1, const float* __restrict__ b1,
    const float* __restrict__ W2, const float* __restrict__ b2,
    const float* __restrict__ Wdec, const float* __restrict__ bdec,
    float* __restrict__ out)
{
  const int n = blockIdx.x;
  const int t = threadIdx.x;
  __shared__ float ctxs[EE];
  __shared__ float hsh[32];
  __shared__ float qsh[2];
  __shared__ float red[4];

  const float* gm = &g_m[n * NSPLIT];
  const float* gl = &g_l[n * NSPLIT];
  float M = -1e30f;
  for (int s = 0; s < NSPLIT; ++s) M = fmaxf(M, gm[s]);
  float L = 0.f;
  for (int s = 0; s < NSPLIT; ++s) L += gl[s] * expf(gm[s] - M);
  if (t < EE) {
    float c = 0.f;
    for (int s = 0; s < NSPLIT; ++s)
      c += expf(gm[s] - M) * g_ctx[((size_t)n * NSPLIT + s) * EE + t];
    ctxs[t] = c / L;
  }
  __syncthreads();
  if (t < 32) {
    float h = b1[t];
    for (int e = 0; e < EE; ++e) h += ctxs[e] * W1[e * 32 + t];
    hsh[t] = fmaxf(h, 0.f);
  }
  __syncthreads();
  if (t == 0) {
    float p0 = b2[0], p1 = b2[1];
    #pragma unroll
    for (int k = 0; k < 32; ++k) { p0 += hsh[k] * W2[k * 2]; p1 += hsh[k] * W2[k * 2 + 1]; }
    float inv = 1.f / fmaxf(sqrtf(p0 * p0 + p1 * p1), 1e-12f);
    float q0 = p0 * inv, q1 = p1 * inv;
    const float PI2 = 6.2831853071795864769f;
    float ang = atan2f(q1, q0) + PI2;
    if (ang >= PI2) ang -= PI2;
    out[n * 2 + 0] = q0;
    out[n * 2 + 1] = q1;
    out[2 * NN + n] = ang;
    qsh[0] = q0; qsh[1] = q1;
  }
  __syncthreads();
  const float q0 = qsh[0], q1 = qsh[1];

  float ss = 0.f;
  for (int i = t; i < GG / 4; i += 256) {
    float4 w0 = *(const float4*)&Wdec[i * 4];
    float4 w1 = *(const float4*)&Wdec[GG + i * 4];
    float4 bd = *(const float4*)&bdec[i * 4];
    float v0 = q0 * w0.x + q1 * w1.x + bd.x;
    float v1 = q0 * w0.y + q1 * w1.y + bd.y;
    float v2 = q0 * w0.z + q1 * w1.z + bd.z;
    float v3 = q0 * w0.w + q1 * w1.w + bd.w;
    ss += v0 * v0 + v1 * v1 + v2 * v2 + v3 * v3;
  }
  #pragma unroll
  for (int off = 32; off >= 1; off >>= 1) ss += __shfl_xor(ss, off);
  if ((t & 63) == 0) red[t >> 6] = ss;
  __syncthreads();
  const float inv = 1.f / fmaxf(sqrtf(red[0] + red[1] + red[2] + red[3]), 1e-12f);

  float* orec = out + 3 * NN + (size_t)n * GG;
  for (int i = t; i < GG / 4; i += 256) {
    float4 w0 = *(const float4*)&Wdec[i * 4];
    float4 w1 = *(const float4*)&Wdec[GG + i * 4];
    float4 bd = *(const float4*)&bdec[i * 4];
    float4 o;
    o.x = (q0 * w0.x + q1 * w1.x + bd.x) * inv;
    o.y = (q0 * w0.y + q1 * w1.y + bd.y) * inv;
    o.z = (q0 * w0.z + q1 * w1.z + bd.z) * inv;
    o.w = (q0 * w0.w + q1 * w1.w + bd.w) * inv;
    *(float4*)&orec[i * 4] = o;
  }
}

// ---------------------------------------------------------------------------
extern "C" void kernel_launch(void* const* d_in, const int* in_sizes, int n_in,
                              void* d_out, int out_size, void* d_ws, size_t ws_size,
                              hipStream_t stream) {
  (void)in_sizes; (void)n_in; (void)out_size; (void)d_ws; (void)ws_size;
  const float* x    = (const float*)d_in[0];
  const int*   tidx = (const int*)  d_in[1];
  const int*   pidx = (const int*)  d_in[2];
  const float* Wp   = (const float*)d_in[3];
  const float* bp   = (const float*)d_in[4];
  const float* tt   = (const float*)d_in[5];
  const float* W1   = (const float*)d_in[6];
  const float* b1   = (const float*)d_in[7];
  const float* W2   = (const float*)d_in[8];
  const float* b2   = (const float*)d_in[9];
  const float* Wdec = (const float*)d_in[10];
  const float* bdec = (const float*)d_in[11];
  float* out = (float*)d_out;

  float* xT;
  hipGetSymbolAddress((void**)&xT, HIP_SYMBOL(g_xT));

  dim3 gridT((GG + 63) / 64, NN / 64, 1);       // 313 x 32
  transpose_kernel<<<gridT, 256, 0, stream>>>(x, xT);

  dim3 gridA(NN / TN, NSPLIT, 1);               // 16 x 50
  proj_attn_kernel<<<gridA, 256, 0, stream>>>(xT, tidx, pidx, Wp, bp, tt);

  rec_combine_kernel<<<NN, 256, 0, stream>>>(W1, b1, W2, b2, Wdec, bdec, out);
}

// Round 4
// 402.935 us; speedup vs baseline: 2.1927x; 1.2175x over previous
//
#include <hip/hip_runtime.h>
#include <cmath>

#define GG 20000
#define NN 2048
#define PP 200
#define SS 128
#define EE 128
#define TN 128
#define TPP 4
#define NSPLIT 50

typedef __bf16 bf16x8 __attribute__((ext_vector_type(8)));
typedef float f32x16 __attribute__((ext_vector_type(16)));
typedef unsigned short u16x8 __attribute__((ext_vector_type(8)));

// static device scratch
__device__ __align__(16) unsigned short g_xTh[(size_t)GG * NN];   // 82 MB
__device__ __align__(16) unsigned short g_xTl[(size_t)GG * NN];   // 82 MB
__device__ __align__(16) unsigned short g_Wh[(size_t)PP * EE * SS];
__device__ __align__(16) unsigned short g_Wl[(size_t)PP * EE * SS];
__device__ float g_ctx[(size_t)NN * NSPLIT * EE];                 // 52 MB
__device__ float g_m[NN * NSPLIT];
__device__ float g_l[NN * NSPLIT];
__device__ float g_pcn[NN * 2];

__device__ __forceinline__ unsigned short f2bf(float f) {
  unsigned u = __builtin_bit_cast(unsigned, f);
  return (unsigned short)((u + 0x7FFFu + ((u >> 16) & 1u)) >> 16);
}
__device__ __forceinline__ float bf2f(unsigned short h) {
  return __builtin_bit_cast(float, (unsigned)h << 16);
}

// ---------------------------------------------------------------------------
// Phase 0a: transpose x (2048 x 20000) -> xTh/xTl bf16 (20000 x 2048)
// ---------------------------------------------------------------------------
__global__ __launch_bounds__(256) void transpose_convert_kernel(
    const float* __restrict__ x)
{
  __shared__ float tile[64][65];
  const int g0 = blockIdx.x * 64;
  const int n0 = blockIdx.y * 64;
  const int t = threadIdx.x;
  {
    const int gq = t & 15, nl4 = t >> 4;
    #pragma unroll
    for (int k = 0; k < 4; ++k) {
      int nl = nl4 + 16 * k;
      int g = g0 + gq * 4;
      if (g + 3 < GG) {
        float4 v = *(const float4*)&x[(size_t)(n0 + nl) * GG + g];
        tile[gq * 4 + 0][nl] = v.x;
        tile[gq * 4 + 1][nl] = v.y;
        tile[gq * 4 + 2][nl] = v.z;
        tile[gq * 4 + 3][nl] = v.w;
      }
    }
  }
  __syncthreads();
  {
    const int nq = t & 15, gl4 = t >> 4;
    #pragma unroll
    for (int k = 0; k < 4; ++k) {
      int gl = gl4 + 16 * k;
      int g = g0 + gl;
      if (g < GG) {
        ushort4 hv, lv;
        float f0 = tile[gl][nq * 4 + 0];
        float f1 = tile[gl][nq * 4 + 1];
        float f2 = tile[gl][nq * 4 + 2];
        float f3 = tile[gl][nq * 4 + 3];
        hv.x = f2bf(f0); hv.y = f2bf(f1); hv.z = f2bf(f2); hv.w = f2bf(f3);
        lv.x = f2bf(f0 - bf2f(hv.x));
        lv.y = f2bf(f1 - bf2f(hv.y));
        lv.z = f2bf(f2 - bf2f(hv.z));
        lv.w = f2bf(f3 - bf2f(hv.w));
        size_t base = (size_t)g * NN + n0 + nq * 4;
        *(ushort4*)&g_xTh[base] = hv;
        *(ushort4*)&g_xTl[base] = lv;
      }
    }
  }
}

// ---------------------------------------------------------------------------
// Phase 0b: convert W_proj to bf16 hi/lo
// ---------------------------------------------------------------------------
__global__ __launch_bounds__(256) void wconvert_kernel(const float* __restrict__ Wp)
{
  size_t i = ((size_t)blockIdx.x * 256 + threadIdx.x) * 4;
  float4 v = *(const float4*)&Wp[i];
  ushort4 hv, lv;
  hv.x = f2bf(v.x); hv.y = f2bf(v.y); hv.z = f2bf(v.z); hv.w = f2bf(v.w);
  lv.x = f2bf(v.x - bf2f(hv.x));
  lv.y = f2bf(v.y - bf2f(hv.y));
  lv.z = f2bf(v.z - bf2f(hv.z));
  lv.w = f2bf(v.w - bf2f(hv.w));
  *(ushort4*)&g_Wh[i] = hv;
  *(ushort4*)&g_Wl[i] = lv;
}

// ---------------------------------------------------------------------------
// Phase A: MFMA projection + relu + score + online-softmax partials.
// grid (16, 50), block 256 (4 waves).  Block: 128 n x 4 pathways.
// Wave w owns n-cols [n0+32w, +32).  D[e,n] = W[e,s] x[s,n] (swapped).
// 32x32x16 bf16, 3 products (hh, hl, lh).
// LDS 64 KB: wAh/wAl [128 e][8 slots of 8 s] XOR-swizzled; xgh/xgl [64 s][128 n].
// ---------------------------------------------------------------------------
__global__ __launch_bounds__(256, 2) void proj_mfma_kernel(
    const int* __restrict__ tidx, const int* __restrict__ pidx,
    const float* __restrict__ bp, const float* __restrict__ tt)
{
  __shared__ __align__(16) unsigned char lds_raw[65536];
  unsigned short* wAh = (unsigned short*)lds_raw;            // [128][64] swz
  unsigned short* wAl = wAh + 128 * 64;
  unsigned short* xgh = wAl + 128 * 64;                      // [64][128]
  unsigned short* xgl = xgh + 64 * 128;
  float* tbuf = (float*)lds_raw;                             // epilogue [4][32][128] swz

  const int t = threadIdx.x;
  const int w = t >> 6;
  const int ln = t & 63;
  const int nl = ln & 31;
  const int kh = ln >> 5;          // k-half
  const int h8 = kh * 8;
  const int n0 = blockIdx.x * TN;
  const int split = blockIdx.y;
  const int ncol = n0 + w * 32 + nl;
  const int tid_n = tidx[ncol];

  f32x16 ctx[4];
  #pragma unroll
  for (int et = 0; et < 4; ++et)
    #pragma unroll
    for (int r = 0; r < 16; ++r) ctx[et][r] = 0.f;
  float m_r = -1e30f, l_r = 0.f;

  for (int pp = 0; pp < TPP; ++pp) {
    const int p = split * TPP + pp;
    f32x16 acc[4];
    #pragma unroll
    for (int et = 0; et < 4; ++et)
      #pragma unroll
      for (int r = 0; r < 16; ++r) acc[et][r] = 0.f;

    for (int ch = 0; ch < 2; ++ch) {
      __syncthreads();   // previous chunk fully consumed
      // --- stage W chunk: rows e=0..127, s-cols [ch*64, +64), XOR-slot swizzle
      {
        const int e = t >> 1, soff = (t & 1) * 32;
        const size_t gb = (size_t)p * (EE * SS) + (size_t)e * SS + ch * 64 + soff;
        const uint4* srch = (const uint4*)(g_Wh + gb);
        const uint4* srcl = (const uint4*)(g_Wl + gb);
        #pragma unroll
        for (int j = 0; j < 4; ++j) {
          int slot = (t & 1) * 4 + j;
          int slp = slot ^ (e & 7);
          *(uint4*)(wAh + e * 64 + slp * 8) = srch[j];
          *(uint4*)(wAl + e * 64 + slp * 8) = srcl[j];
        }
      }
      // --- stage xg chunk: [s][n] natural, coalesced gather from xT
      {
        const int no8 = (t & 15) * 8;
        const int sr = t >> 4;     // 0..15
        #pragma unroll
        for (int ps = 0; ps < 4; ++ps) {
          int s = sr + ps * 16;
          int g = pidx[p * SS + ch * 64 + s];
          size_t gb = (size_t)g * NN + n0 + no8;
          *(uint4*)(xgh + s * 128 + no8) = *(const uint4*)(g_xTh + gb);
          *(uint4*)(xgl + s * 128 + no8) = *(const uint4*)(g_xTl + gb);
        }
      }
      __syncthreads();
      // --- MFMA inner loop
      #pragma unroll
      for (int ks = 0; ks < 4; ++ks) {
        u16x8 bhu, blu;
        const int sbase = (ks * 16 + h8) * 128 + w * 32 + nl;
        #pragma unroll
        for (int j = 0; j < 8; ++j) {
          bhu[j] = xgh[sbase + j * 128];
          blu[j] = xgl[sbase + j * 128];
        }
        bf16x8 bh = __builtin_bit_cast(bf16x8, bhu);
        bf16x8 bl = __builtin_bit_cast(bf16x8, blu);
        #pragma unroll
        for (int et = 0; et < 4; ++et) {
          const int e = et * 32 + nl;
          const int slp = (ks * 2 + kh) ^ (e & 7);
          bf16x8 ah = __builtin_bit_cast(bf16x8, *(const uint4*)(wAh + e * 64 + slp * 8));
          bf16x8 al = __builtin_bit_cast(bf16x8, *(const uint4*)(wAl + e * 64 + slp * 8));
          acc[et] = __builtin_amdgcn_mfma_f32_32x32x16_bf16(ah, bh, acc[et], 0, 0, 0);
          acc[et] = __builtin_amdgcn_mfma_f32_32x32x16_bf16(ah, bl, acc[et], 0, 0, 0);
          acc[et] = __builtin_amdgcn_mfma_f32_32x32x16_bf16(al, bh, acc[et], 0, 0, 0);
        }
      }
    }

    // --- bias + relu + score (per-lane column), online softmax update
    const float4* qp = (const float4*)(tt + (size_t)tid_n * EE);
    const float4* bpv = (const float4*)(bp + (size_t)p * EE);
    float scr = 0.f;
    #pragma unroll
    for (int et = 0; et < 4; ++et)
      #pragma unroll
      for (int rq = 0; rq < 4; ++rq) {
        int e4 = (et * 32 + rq * 8 + kh * 4) >> 2;
        float4 q4 = qp[e4];
        float4 b4 = bpv[e4];
        float h0 = fmaxf(acc[et][rq * 4 + 0] + b4.x, 0.f);
        float h1 = fmaxf(acc[et][rq * 4 + 1] + b4.y, 0.f);
        float h2 = fmaxf(acc[et][rq * 4 + 2] + b4.z, 0.f);
        float h3 = fmaxf(acc[et][rq * 4 + 3] + b4.w, 0.f);
        acc[et][rq * 4 + 0] = h0; acc[et][rq * 4 + 1] = h1;
        acc[et][rq * 4 + 2] = h2; acc[et][rq * 4 + 3] = h3;
        scr += h0 * q4.x + h1 * q4.y + h2 * q4.z + h3 * q4.w;
      }
    scr += __shfl_xor(scr, 32);
    const float s_r = scr * 0.08838834764831845f;
    const float mn = fmaxf(m_r, s_r);
    const float f = expf(m_r - mn);
    const float wg = expf(s_r - mn);
    l_r = l_r * f + wg;
    m_r = mn;
    #pragma unroll
    for (int et = 0; et < 4; ++et)
      #pragma unroll
      for (int r = 0; r < 16; ++r)
        ctx[et][r] = ctx[et][r] * f + wg * acc[et][r];
  }

  // --- epilogue: LDS transpose ctx -> coalesced g_ctx[n][split][e]
  __syncthreads();                 // all MFMA reads of wA/xg done
  float* tb = tbuf + w * (32 * 128);
  #pragma unroll
  for (int et = 0; et < 4; ++et)
    #pragma unroll
    for (int rq = 0; rq < 4; ++rq) {
      int slot = et * 8 + rq * 2 + kh;          // e-quad index 0..31
      float4 v = make_float4(ctx[et][rq * 4 + 0], ctx[et][rq * 4 + 1],
                             ctx[et][rq * 4 + 2], ctx[et][rq * 4 + 3]);
      *(float4*)&tb[nl * 128 + ((slot ^ nl) << 2)] = v;
    }
  __syncthreads();
  {
    const int rrow = ln >> 1, eh = (ln & 1) * 16;  // eh = slot base
    const int nn = n0 + w * 32 + rrow;
    float* dst = g_ctx + ((size_t)nn * NSPLIT + split) * EE + eh * 4;
    const float* srcrow = tb + rrow * 128;
    #pragma unroll
    for (int k = 0; k < 16; ++k) {
      int slot = eh + k;
      *(float4*)&dst[k * 4] = *(const float4*)&srcrow[(slot ^ rrow) << 2];
    }
  }
  if (ln < 32) {
    g_m[(size_t)ncol * NSPLIT + split] = m_r;
    g_l[(size_t)ncol * NSPLIT + split] = l_r;
  }
}

// ---------------------------------------------------------------------------
// Phase B: merge splits + MLP + pcn/ang.  grid 2048, block 128.
// ---------------------------------------------------------------------------
__global__ __launch_bounds__(128) void combine_kernel(
    const float* __restrict__ W1, const float* __restrict__ b1,
    const float* __restrict__ W2, const float* __restrict__ b2,
    float* __restrict__ out)
{
  const int n = blockIdx.x;
  const int t = threadIdx.x;
  __shared__ float sm[NSPLIT], slv[NSPLIT], ws[NSPLIT], ctxs[EE], hsh[32];

  if (t < NSPLIT) sm[t] = g_m[(size_t)n * NSPLIT + t];
  else if (t < 2 * NSPLIT) slv[t - NSPLIT] = g_l[(size_t)n * NSPLIT + t - NSPLIT];
  __syncthreads();
  if (t < NSPLIT) {
    float M = -1e30f;
    for (int s = 0; s < NSPLIT; ++s) M = fmaxf(M, sm[s]);
    ws[t] = expf(sm[t] - M);
  }
  __syncthreads();
  float L = 0.f;
  for (int s = 0; s < NSPLIT; ++s) L += slv[s] * ws[s];
  float c = 0.f;
  for (int s = 0; s < NSPLIT; ++s)
    c += ws[s] * g_ctx[((size_t)n * NSPLIT + s) * EE + t];
  ctxs[t] = c / L;
  __syncthreads();
  if (t < 32) {
    float h = b1[t];
    for (int e = 0; e < EE; ++e) h += ctxs[e] * W1[e * 32 + t];
    hsh[t] = fmaxf(h, 0.f);
  }
  __syncthreads();
  if (t == 0) {
    float p0 = b2[0], p1 = b2[1];
    #pragma unroll
    for (int k = 0; k < 32; ++k) { p0 += hsh[k] * W2[k * 2]; p1 += hsh[k] * W2[k * 2 + 1]; }
    float inv = 1.f / fmaxf(sqrtf(p0 * p0 + p1 * p1), 1e-12f);
    float q0 = p0 * inv, q1 = p1 * inv;
    const float PI2 = 6.2831853071795864769f;
    float ang = atan2f(q1, q0) + PI2;
    if (ang >= PI2) ang -= PI2;
    out[n * 2 + 0] = q0;
    out[n * 2 + 1] = q1;
    out[2 * NN + n] = ang;
    g_pcn[n * 2 + 0] = q0;
    g_pcn[n * 2 + 1] = q1;
  }
}

// ---------------------------------------------------------------------------
// Phase C: rec = l2norm(pcn @ Wdec + bdec).  grid 2048, block 256.
// ---------------------------------------------------------------------------
__global__ __launch_bounds__(256) void rec_kernel(
    const float* __restrict__ Wdec, const float* __restrict__ bdec,
    float* __restrict__ out)
{
  const int n = blockIdx.x;
  const int t = threadIdx.x;
  __shared__ float red[4];

  const float q0 = g_pcn[n * 2 + 0];
  const float q1 = g_pcn[n * 2 + 1];

  float ss = 0.f;
  for (int i = t; i < GG / 4; i += 256) {
    float4 w0 = *(const float4*)&Wdec[i * 4];
    float4 w1 = *(const float4*)&Wdec[GG + i * 4];
    float4 bd = *(const float4*)&bdec[i * 4];
    float v0 = q0 * w0.x + q1 * w1.x + bd.x;
    float v1 = q0 * w0.y + q1 * w1.y + bd.y;
    float v2 = q0 * w0.z + q1 * w1.z + bd.z;
    float v3 = q0 * w0.w + q1 * w1.w + bd.w;
    ss += v0 * v0 + v1 * v1 + v2 * v2 + v3 * v3;
  }
  #pragma unroll
  for (int off = 32; off >= 1; off >>= 1) ss += __shfl_xor(ss, off);
  if ((t & 63) == 0) red[t >> 6] = ss;
  __syncthreads();
  const float inv = 1.f / fmaxf(sqrtf(red[0] + red[1] + red[2] + red[3]), 1e-12f);

  float* orec = out + 3 * NN + (size_t)n * GG;
  for (int i = t; i < GG / 4; i += 256) {
    float4 w0 = *(const float4*)&Wdec[i * 4];
    float4 w1 = *(const float4*)&Wdec[GG + i * 4];
    float4 bd = *(const float4*)&bdec[i * 4];
    float4 o;
    o.x = (q0 * w0.x + q1 * w1.x + bd.x) * inv;
    o.y = (q0 * w0.y + q1 * w1.y + bd.y) * inv;
    o.z = (q0 * w0.z + q1 * w1.z + bd.z) * inv;
    o.w = (q0 * w0.w + q1 * w1.w + bd.w) * inv;
    *(float4*)&orec[i * 4] = o;
  }
}

// ---------------------------------------------------------------------------
extern "C" void kernel_launch(void* const* d_in, const int* in_sizes, int n_in,
                              void* d_out, int out_size, void* d_ws, size_t ws_size,
                              hipStream_t stream) {
  (void)in_sizes; (void)n_in; (void)out_size; (void)d_ws; (void)ws_size;
  const float* x    = (const float*)d_in[0];
  const int*   tidx = (const int*)  d_in[1];
  const int*   pidx = (const int*)  d_in[2];
  const float* Wp   = (const float*)d_in[3];
  const float* bp   = (const float*)d_in[4];
  const float* tt   = (const float*)d_in[5];
  const float* W1   = (const float*)d_in[6];
  const float* b1   = (const float*)d_in[7];
  const float* W2   = (const float*)d_in[8];
  const float* b2   = (const float*)d_in[9];
  const float* Wdec = (const float*)d_in[10];
  const float* bdec = (const float*)d_in[11];
  float* out = (float*)d_out;

  dim3 gridT((GG + 63) / 64, NN / 64, 1);   // 313 x 32
  transpose_convert_kernel<<<gridT, 256, 0, stream>>>(x);
  wconvert_kernel<<<(PP * EE * SS) / 1024, 256, 0, stream>>>(Wp);

  dim3 gridA(NN / TN, NSPLIT, 1);           // 16 x 50
  proj_mfma_kernel<<<gridA, 256, 0, stream>>>(tidx, pidx, bp, tt);

  combine_kernel<<<NN, 128, 0, stream>>>(W1, b1, W2, b2, out);
  rec_kernel<<<NN, 256, 0, stream>>>(Wdec, bdec, out);
}

// Round 5
// 347.986 us; speedup vs baseline: 2.5390x; 1.1579x over previous
//
#include <hip/hip_runtime.h>
#include <cmath>

#define GG 20000
#define NN 2048
#define PP 200
#define SS 128
#define EE 128
#define TN 128
#define TPP 4
#define NSPLIT 50

typedef __bf16 bf16x8 __attribute__((ext_vector_type(8)));
typedef float f32x16 __attribute__((ext_vector_type(16)));
typedef unsigned short u16x8 __attribute__((ext_vector_type(8)));

// static device scratch
__device__ __align__(16) unsigned g_xTi[(size_t)GG * NN];            // 164 MB  (h | l<<16)
__device__ __align__(16) unsigned short g_Wsw[(size_t)PP * 2 * 16384]; // 13 MB pre-swizzled
__device__ float g_ctx[(size_t)NN * NSPLIT * EE];                     // 52 MB
__device__ float g_m[NN * NSPLIT];
__device__ float g_l[NN * NSPLIT];
__device__ float g_pcn[NN * 2];

__device__ __forceinline__ unsigned short f2bf(float f) {
  unsigned u = __builtin_bit_cast(unsigned, f);
  return (unsigned short)((u + 0x7FFFu + ((u >> 16) & 1u)) >> 16);
}
__device__ __forceinline__ float bf2f(unsigned short h) {
  return __builtin_bit_cast(float, (unsigned)h << 16);
}
__device__ __forceinline__ unsigned packhl(float f) {
  unsigned short h = f2bf(f);
  unsigned short l = f2bf(f - bf2f(h));
  return (unsigned)h | ((unsigned)l << 16);
}

// ---------------------------------------------------------------------------
// Phase 0a: transpose x (2048 x 20000) -> xTi (20000 x 2048) interleaved hi/lo
// ---------------------------------------------------------------------------
__global__ __launch_bounds__(256) void transpose_convert_kernel(
    const float* __restrict__ x)
{
  __shared__ float tile[64][65];
  const int g0 = blockIdx.x * 64;
  const int n0 = blockIdx.y * 64;
  const int t = threadIdx.x;
  {
    const int gq = t & 15, nl4 = t >> 4;
    #pragma unroll
    for (int k = 0; k < 4; ++k) {
      int nl = nl4 + 16 * k;
      int g = g0 + gq * 4;
      if (g + 3 < GG) {
        float4 v = *(const float4*)&x[(size_t)(n0 + nl) * GG + g];
        tile[gq * 4 + 0][nl] = v.x;
        tile[gq * 4 + 1][nl] = v.y;
        tile[gq * 4 + 2][nl] = v.z;
        tile[gq * 4 + 3][nl] = v.w;
      }
    }
  }
  __syncthreads();
  {
    const int nq = t & 15, gl4 = t >> 4;
    #pragma unroll
    for (int k = 0; k < 4; ++k) {
      int gl = gl4 + 16 * k;
      int g = g0 + gl;
      if (g < GG) {
        uint4 v;
        v.x = packhl(tile[gl][nq * 4 + 0]);
        v.y = packhl(tile[gl][nq * 4 + 1]);
        v.z = packhl(tile[gl][nq * 4 + 2]);
        v.w = packhl(tile[gl][nq * 4 + 3]);
        *(uint4*)&g_xTi[(size_t)g * NN + n0 + nq * 4] = v;
      }
    }
  }
}

// ---------------------------------------------------------------------------
// Phase 0b: W_proj -> pre-swizzled bf16 hi/lo image (LDS-linear order).
// LDS image per (p,ch): h-block 8192 shorts then l-block.  Within block:
// offset = e*64 + slp*8 + si, holding W[p][e][ch*64 + (slp^(e&7))*8 + si].
// ---------------------------------------------------------------------------
__global__ __launch_bounds__(256) void wconvert_kernel(const float* __restrict__ Wp)
{
  unsigned v = blockIdx.x * 256 + threadIdx.x;   // [0, 200*16384)
  const int si = v & 7;
  const int slp = (v >> 3) & 7;
  const int e = (v >> 6) & 127;
  const int ch = (v >> 13) & 1;
  const int p = v >> 14;
  const int slot = slp ^ (e & 7);
  const int s = ch * 64 + slot * 8 + si;
  float f = Wp[((size_t)p * EE + e) * SS + s];
  unsigned short h = f2bf(f);
  unsigned short l = f2bf(f - bf2f(h));
  size_t base = (size_t)(p * 2 + ch) * 16384 + e * 64 + slp * 8 + si;
  g_Wsw[base] = h;
  g_Wsw[base + 8192] = l;
}

// ---------------------------------------------------------------------------
// proj helpers
// ---------------------------------------------------------------------------
__device__ __forceinline__ void stage_w(int p, int ch, unsigned short* ldsbase,
                                        int w, int ln) {
  const unsigned short* src = g_Wsw + (size_t)(p * 2 + ch) * 16384 + w * 4096 + ln * 8;
  unsigned short* ld = ldsbase + w * 4096;
  #pragma unroll
  for (int j = 0; j < 8; ++j) {
    __builtin_amdgcn_global_load_lds(
        (const __attribute__((address_space(1))) unsigned int*)(src + j * 512),
        (__attribute__((address_space(3))) unsigned int*)(ld + j * 512), 16, 0, 0);
  }
}

__device__ __forceinline__ void load_x(const int* __restrict__ pidx, int p, int ch,
                                       int kh, int ncol, unsigned* xr) {
  const int* pg = pidx + p * SS + ch * 64 + kh * 8;
  #pragma unroll
  for (int ks = 0; ks < 4; ++ks)
    #pragma unroll
    for (int j = 0; j < 8; ++j) {
      int g = pg[ks * 16 + j];
      xr[ks * 8 + j] = g_xTi[(size_t)g * NN + ncol];
    }
}

__device__ __forceinline__ void compute_chunk(const unsigned short* wb,
                                              const unsigned* xr, f32x16* acc,
                                              int nl, int kh) {
  const unsigned short* wAh = wb;
  const unsigned short* wAl = wb + 8192;
  #pragma unroll
  for (int ks = 0; ks < 4; ++ks) {
    u16x8 bhu, blu;
    #pragma unroll
    for (int j = 0; j < 8; ++j) {
      unsigned v = xr[ks * 8 + j];
      bhu[j] = (unsigned short)(v & 0xffffu);
      blu[j] = (unsigned short)(v >> 16);
    }
    bf16x8 bh = __builtin_bit_cast(bf16x8, bhu);
    bf16x8 bl = __builtin_bit_cast(bf16x8, blu);
    #pragma unroll
    for (int et = 0; et < 4; ++et) {
      const int e = et * 32 + nl;
      const int slp = (ks * 2 + kh) ^ (e & 7);
      bf16x8 ah = __builtin_bit_cast(bf16x8, *(const uint4*)(wAh + e * 64 + slp * 8));
      bf16x8 al = __builtin_bit_cast(bf16x8, *(const uint4*)(wAl + e * 64 + slp * 8));
      acc[et] = __builtin_amdgcn_mfma_f32_32x32x16_bf16(ah, bh, acc[et], 0, 0, 0);
      acc[et] = __builtin_amdgcn_mfma_f32_32x32x16_bf16(ah, bl, acc[et], 0, 0, 0);
      acc[et] = __builtin_amdgcn_mfma_f32_32x32x16_bf16(al, bh, acc[et], 0, 0, 0);
    }
  }
}

// ---------------------------------------------------------------------------
// Phase A: MFMA projection + relu + score + online-softmax partials.
// grid (16, 50), block 256 (4 waves).  2-phase pipeline: W dbuf via
// global_load_lds (pre-swizzled source), x direct global->reg prefetch.
// ---------------------------------------------------------------------------
__global__ __launch_bounds__(256, 2) void proj_mfma_kernel(
    const int* __restrict__ tidx, const int* __restrict__ pidx,
    const float* __restrict__ bp, const float* __restrict__ tt)
{
  __shared__ __align__(16) unsigned short wbuf[2][16384];   // 64 KB

  const int t = threadIdx.x;
  const int w = t >> 6;
  const int ln = t & 63;
  const int nl = ln & 31;
  const int kh = ln >> 5;
  const int n0 = blockIdx.x * TN;
  const int split = blockIdx.y;
  const int ncol = n0 + w * 32 + nl;
  const int tid_n = tidx[ncol];

  f32x16 ctx[4];
  #pragma unroll
  for (int et = 0; et < 4; ++et)
    #pragma unroll
    for (int r = 0; r < 16; ++r) ctx[et][r] = 0.f;
  float m_r = -1e30f, l_r = 0.f;

  unsigned xA[32], xB[32];

  // prologue: stage chunk (p0, ch0)
  {
    const int p = split * TPP;
    stage_w(p, 0, wbuf[0], w, ln);
    load_x(pidx, p, 0, kh, ncol, xA);
  }
  __syncthreads();

  for (int pp = 0; pp < TPP; ++pp) {
    const int p = split * TPP + pp;
    f32x16 acc[4];
    #pragma unroll
    for (int et = 0; et < 4; ++et)
      #pragma unroll
      for (int r = 0; r < 16; ++r) acc[et][r] = 0.f;

    // chunk 0: consume wbuf[0]/xA, stage wbuf[1]/xB (same pathway ch1)
    stage_w(p, 1, wbuf[1], w, ln);
    load_x(pidx, p, 1, kh, ncol, xB);
    compute_chunk(wbuf[0], xA, acc, nl, kh);
    __syncthreads();

    // chunk 1: consume wbuf[1]/xB, stage wbuf[0]/xA (next pathway ch0)
    if (pp + 1 < TPP) {
      stage_w(p + 1, 0, wbuf[0], w, ln);
      load_x(pidx, p + 1, 0, kh, ncol, xA);
    }
    compute_chunk(wbuf[1], xB, acc, nl, kh);

    // bias + relu + score, online softmax update
    const float4* qp = (const float4*)(tt + (size_t)tid_n * EE);
    const float4* bpv = (const float4*)(bp + (size_t)p * EE);
    float scr = 0.f;
    #pragma unroll
    for (int et = 0; et < 4; ++et)
      #pragma unroll
      for (int rq = 0; rq < 4; ++rq) {
        int e4 = (et * 32 + rq * 8 + kh * 4) >> 2;
        float4 q4 = qp[e4];
        float4 b4 = bpv[e4];
        float h0 = fmaxf(acc[et][rq * 4 + 0] + b4.x, 0.f);
        float h1 = fmaxf(acc[et][rq * 4 + 1] + b4.y, 0.f);
        float h2 = fmaxf(acc[et][rq * 4 + 2] + b4.z, 0.f);
        float h3 = fmaxf(acc[et][rq * 4 + 3] + b4.w, 0.f);
        acc[et][rq * 4 + 0] = h0; acc[et][rq * 4 + 1] = h1;
        acc[et][rq * 4 + 2] = h2; acc[et][rq * 4 + 3] = h3;
        scr += h0 * q4.x + h1 * q4.y + h2 * q4.z + h3 * q4.w;
      }
    scr += __shfl_xor(scr, 32);
    const float s_r = scr * 0.08838834764831845f;
    const float mn = fmaxf(m_r, s_r);
    const float f = expf(m_r - mn);
    const float wg = expf(s_r - mn);
    l_r = l_r * f + wg;
    m_r = mn;
    #pragma unroll
    for (int et = 0; et < 4; ++et)
      #pragma unroll
      for (int r = 0; r < 16; ++r)
        ctx[et][r] = ctx[et][r] * f + wg * acc[et][r];

    __syncthreads();
  }

  // --- epilogue: LDS transpose ctx -> coalesced g_ctx[n][split][e]
  float* tbuf = (float*)wbuf;
  float* tb = tbuf + w * (32 * 128);
  #pragma unroll
  for (int et = 0; et < 4; ++et)
    #pragma unroll
    for (int rq = 0; rq < 4; ++rq) {
      int slot = et * 8 + rq * 2 + kh;          // e-quad index 0..31
      float4 v = make_float4(ctx[et][rq * 4 + 0], ctx[et][rq * 4 + 1],
                             ctx[et][rq * 4 + 2], ctx[et][rq * 4 + 3]);
      *(float4*)&tb[nl * 128 + ((slot ^ nl) << 2)] = v;
    }
  __syncthreads();
  {
    const int rrow = ln >> 1, eh = (ln & 1) * 16;
    const int nn = n0 + w * 32 + rrow;
    float* dst = g_ctx + ((size_t)nn * NSPLIT + split) * EE + eh * 4;
    const float* srcrow = tb + rrow * 128;
    #pragma unroll
    for (int k = 0; k < 16; ++k) {
      int slot = eh + k;
      *(float4*)&dst[k * 4] = *(const float4*)&srcrow[(slot ^ rrow) << 2];
    }
  }
  if (ln < 32) {
    g_m[(size_t)ncol * NSPLIT + split] = m_r;
    g_l[(size_t)ncol * NSPLIT + split] = l_r;
  }
}

// ---------------------------------------------------------------------------
// Phase B: merge splits + MLP + pcn/ang.  grid 2048, block 128.
// ---------------------------------------------------------------------------
__global__ __launch_bounds__(128) void combine_kernel(
    const float* __restrict__ W1, const float* __restrict__ b1,
    const float* __restrict__ W2, const float* __restrict__ b2,
    float* __restrict__ out)
{
  const int n = blockIdx.x;
  const int t = threadIdx.x;
  __shared__ float sm[NSPLIT], slv[NSPLIT], ws[NSPLIT], ctxs[EE], hsh[32];

  if (t < NSPLIT) sm[t] = g_m[(size_t)n * NSPLIT + t];
  else if (t < 2 * NSPLIT) slv[t - NSPLIT] = g_l[(size_t)n * NSPLIT + t - NSPLIT];
  __syncthreads();
  if (t < NSPLIT) {
    float M = -1e30f;
    for (int s = 0; s < NSPLIT; ++s) M = fmaxf(M, sm[s]);
    ws[t] = expf(sm[t] - M);
  }
  __syncthreads();
  float L = 0.f;
  for (int s = 0; s < NSPLIT; ++s) L += slv[s] * ws[s];
  float c = 0.f;
  for (int s = 0; s < NSPLIT; ++s)
    c += ws[s] * g_ctx[((size_t)n * NSPLIT + s) * EE + t];
  ctxs[t] = c / L;
  __syncthreads();
  if (t < 32) {
    float h = b1[t];
    for (int e = 0; e < EE; ++e) h += ctxs[e] * W1[e * 32 + t];
    hsh[t] = fmaxf(h, 0.f);
  }
  __syncthreads();
  if (t == 0) {
    float p0 = b2[0], p1 = b2[1];
    #pragma unroll
    for (int k = 0; k < 32; ++k) { p0 += hsh[k] * W2[k * 2]; p1 += hsh[k] * W2[k * 2 + 1]; }
    float inv = 1.f / fmaxf(sqrtf(p0 * p0 + p1 * p1), 1e-12f);
    float q0 = p0 * inv, q1 = p1 * inv;
    const float PI2 = 6.2831853071795864769f;
    float ang = atan2f(q1, q0) + PI2;
    if (ang >= PI2) ang -= PI2;
    out[n * 2 + 0] = q0;
    out[n * 2 + 1] = q1;
    out[2 * NN + n] = ang;
    g_pcn[n * 2 + 0] = q0;
    g_pcn[n * 2 + 1] = q1;
  }
}

// ---------------------------------------------------------------------------
// Phase C: rec = l2norm(pcn @ Wdec + bdec).  grid 2048, block 256.
// ---------------------------------------------------------------------------
__global__ __launch_bounds__(256) void rec_kernel(
    const float* __restrict__ Wdec, const float* __restrict__ bdec,
    float* __restrict__ out)
{
  const int n = blockIdx.x;
  const int t = threadIdx.x;
  __shared__ float red[4];

  const float q0 = g_pcn[n * 2 + 0];
  const float q1 = g_pcn[n * 2 + 1];

  float ss = 0.f;
  for (int i = t; i < GG / 4; i += 256) {
    float4 w0 = *(const float4*)&Wdec[i * 4];
    float4 w1 = *(const float4*)&Wdec[GG + i * 4];
    float4 bd = *(const float4*)&bdec[i * 4];
    float v0 = q0 * w0.x + q1 * w1.x + bd.x;
    float v1 = q0 * w0.y + q1 * w1.y + bd.y;
    float v2 = q0 * w0.z + q1 * w1.z + bd.z;
    float v3 = q0 * w0.w + q1 * w1.w + bd.w;
    ss += v0 * v0 + v1 * v1 + v2 * v2 + v3 * v3;
  }
  #pragma unroll
  for (int off = 32; off >= 1; off >>= 1) ss += __shfl_xor(ss, off);
  if ((t & 63) == 0) red[t >> 6] = ss;
  __syncthreads();
  const float inv = 1.f / fmaxf(sqrtf(red[0] + red[1] + red[2] + red[3]), 1e-12f);

  float* orec = out + 3 * NN + (size_t)n * GG;
  for (int i = t; i < GG / 4; i += 256) {
    float4 w0 = *(const float4*)&Wdec[i * 4];
    float4 w1 = *(const float4*)&Wdec[GG + i * 4];
    float4 bd = *(const float4*)&bdec[i * 4];
    float4 o;
    o.x = (q0 * w0.x + q1 * w1.x + bd.x) * inv;
    o.y = (q0 * w0.y + q1 * w1.y + bd.y) * inv;
    o.z = (q0 * w0.z + q1 * w1.z + bd.z) * inv;
    o.w = (q0 * w0.w + q1 * w1.w + bd.w) * inv;
    *(float4*)&orec[i * 4] = o;
  }
}

// ---------------------------------------------------------------------------
extern "C" void kernel_launch(void* const* d_in, const int* in_sizes, int n_in,
                              void* d_out, int out_size, void* d_ws, size_t ws_size,
                              hipStream_t stream) {
  (void)in_sizes; (void)n_in; (void)out_size; (void)d_ws; (void)ws_size;
  const float* x    = (const float*)d_in[0];
  const int*   tidx = (const int*)  d_in[1];
  const int*   pidx = (const int*)  d_in[2];
  const float* Wp   = (const float*)d_in[3];
  const float* bp   = (const float*)d_in[4];
  const float* tt   = (const float*)d_in[5];
  const float* W1   = (const float*)d_in[6];
  const float* b1   = (const float*)d_in[7];
  const float* W2   = (const float*)d_in[8];
  const float* b2   = (const float*)d_in[9];
  const float* Wdec = (const float*)d_in[10];
  const float* bdec = (const float*)d_in[11];
  float* out = (float*)d_out;

  dim3 gridT((GG + 63) / 64, NN / 64, 1);   // 313 x 32
  transpose_convert_kernel<<<gridT, 256, 0, stream>>>(x);
  wconvert_kernel<<<(PP * 16384) / 256, 256, 0, stream>>>(Wp);

  dim3 gridA(NN / TN, NSPLIT, 1);           // 16 x 50
  proj_mfma_kernel<<<gridA, 256, 0, stream>>>(tidx, pidx, bp, tt);

  combine_kernel<<<NN, 128, 0, stream>>>(W1, b1, W2, b2, out);
  rec_kernel<<<NN, 256, 0, stream>>>(Wdec, bdec, out);
}